// Round 8
// baseline (237.729 us; speedup 1.0000x reference)
//
#include <hip/hip_runtime.h>

// incidence_matrix_learn on MI355X — round 16.
// Round-15 post-mortem: m97-clone WORKED (lse 92->69.6us, clean counters:
// VGPR 120, no spill, FETCH 50MB = dataset). Remaining stall: 2 blocks/CU
// (LDS 69KB) + __syncthreads vmcnt(0)-drain every K-step -> ~8K cyc/K-step
// vs ~500 cyc pipe work (all pipes <17%). Fix both on the now-clean
// structure: (1) BK=32 ring-3 LDS chunks (53KB total -> 3 blocks/CU, 12
// waves); (2) counted s_waitcnt vmcnt(4) + raw s_barrier (T3/T4), prefetch
// distance 2, never drain mid-loop; 16-chunk full unroll = compile-time
// ring slots. K-accumulation order unchanged -> bitwise-identical output.
// (r9's counted-vmcnt null is explained: hidden A-reloads scrambled the
// count; none exist now.) Also folded cnt_kernel into loss_reduce (per-
// block LDS label histogram, ~1us) — one fewer dispatch.
// Validated algebra (rounds 1-15, absmax 0.0): top-k no-op; P via labels;
// fixed-shift-10 LSE (denom includes self; pos excludes); bf16 nhat;
// cnt = label-histogram - 1; disjoint sp slots; frag-order LDS staging;
// wave-uniform global_load_lds dst.

#define DDIM 512
#define BATCH 64
#define NGID 65536   // 64*640 + 64*384 node-row slots across both scales

typedef __attribute__((ext_vector_type(8))) short short8;
typedef __attribute__((ext_vector_type(4))) float f32x4;

// Triangular tile-pair list (128-granularity): 15 scale0 + 6 scale1.
__constant__ int PAIR_SCALE[21] = {0,0,0,0,0,0,0,0,0,0,0,0,0,0,0, 1,1,1,1,1,1};
__constant__ int PAIR_TU[21]    = {0,0,0,0,0,1,1,1,1,2,2,2,3,3,4, 0,0,0,1,1,2};
__constant__ int PAIR_TV[21]    = {0,1,2,3,4,1,2,3,4,2,3,4,3,4,4, 0,1,2,1,2,2};

__device__ __forceinline__ unsigned short f2bf(float f) {
  unsigned int u = __float_as_uint(f);
  u += 0x7fffu + ((u >> 16) & 1u);   // RNE
  return (unsigned short)(u >> 16);
}

__device__ __forceinline__ void async16(const void* g, void* l) {
  __builtin_amdgcn_global_load_lds(
      (const __attribute__((address_space(1))) unsigned int*)g,
      (__attribute__((address_space(3))) unsigned int*)l, 16, 0, 0);
}

// Fused prep kernel, 256 threads. Blocks [0,1024): adj (both scales) + acc/
// ticket init. Blocks [1024, 1024+16384): normalize, one WAVE per node row.
__global__ __launch_bounds__(256) void prep_kernel(
    const float* __restrict__ enod0, const float* __restrict__ ehy0,
    const float* __restrict__ enod1, const float* __restrict__ ehy1,
    float* __restrict__ adj0, float* __restrict__ adj1,
    int* __restrict__ labels0, int* __restrict__ labels1,
    const float* __restrict__ x0, const float* __restrict__ w0,
    const float* __restrict__ x1, const float* __restrict__ w1,
    unsigned short* __restrict__ nhat0, unsigned short* __restrict__ nhat1,
    float* __restrict__ acc, int* __restrict__ ticket) {
  const int t = threadIdx.x;
  if (blockIdx.x < 1024) {
    // ---- adj path ----
    if (blockIdx.x == 0 && t == 0) { acc[0] = 0.f; acc[1] = 0.f; ticket[0] = 0; }
    const bool s0 = blockIdx.x < 640;
    const int n = s0 ? blockIdx.x : blockIdx.x - 640;
    const int H = s0 ? 128 : 64;
    const float* enod = s0 ? enod0 : enod1;
    const float* ehy = s0 ? ehy0 : ehy1;
    float* out_adj = s0 ? adj0 : adj1;
    int* labels = s0 ? labels0 : labels1;
    __shared__ float erow[DDIM];
    __shared__ float red[128];
    __shared__ int lab;
    if (t < 128) ((float4*)erow)[t] = ((const float4*)(enod + (size_t)n * DDIM))[t];
    if (t == 0) lab = -1;
    __syncthreads();
    float v = 0.f;
    if (t < H) {
      const float4* hr = (const float4*)(ehy + (size_t)t * DDIM);
      float a = 0.f;
      #pragma unroll 8
      for (int d = 0; d < DDIM / 4; ++d) {
        float4 h = hr[d];
        float4 e = ((const float4*)erow)[d];
        a = fmaf(h.x, e.x, a); a = fmaf(h.y, e.y, a);
        a = fmaf(h.z, e.z, a); a = fmaf(h.w, e.w, a);
      }
      v = fmaxf(0.f, 3.0f * a);
    }
    if (t < 128) red[t] = v;
    __syncthreads();
    for (int s = 64; s > 0; s >>= 1) {
      if (t < s) red[t] = fmaxf(red[t], red[t + s]);
      __syncthreads();
    }
    const float mx = red[0];
    __syncthreads();
    const float e = (t < H) ? __expf(v - mx) : 0.f;
    if (t < 128) red[t] = e;
    __syncthreads();
    for (int s = 64; s > 0; s >>= 1) {
      if (t < s) red[t] += red[t + s];
      __syncthreads();
    }
    const float sum = red[0];
    if (t < H) {
      const float adj = e / sum;
      const float bin = (adj > 0.5f) ? 1.0f : 0.0f;
      out_adj[(size_t)n * H + t] = bin;
      if (bin > 0.f) lab = t;
    }
    __syncthreads();
    if (t == 0) labels[n] = lab;
  } else {
    // ---- normalize path: wave per row ----
    const int wave = t >> 6;
    const int lane = t & 63;
    const int g = (blockIdx.x - 1024) * 4 + wave;   // global row id, < 65536
    const bool s0 = g < BATCH * 640;
    const int gg = s0 ? g : g - BATCH * 640;
    const int N = s0 ? 640 : 384;
    const int L = s0 ? 512 : 256;
    const float* x = s0 ? x0 : x1;
    const float* w = s0 ? w0 : w1;
    unsigned short* nhat = s0 ? nhat0 : nhat1;
    const int b = gg / N;
    const int n = gg - b * N;
    const float* src = (n < L) ? (x + ((size_t)b * L + n) * DDIM)
                               : (w + (size_t)(n - L) * DDIM);
    const float4* rowp = (const float4*)src;
    const float4 v0 = rowp[lane];
    const float4 v1 = rowp[lane + 64];
    float ss = v0.x * v0.x + v0.y * v0.y + v0.z * v0.z + v0.w * v0.w +
               v1.x * v1.x + v1.y * v1.y + v1.z * v1.z + v1.w * v1.w;
    #pragma unroll
    for (int off = 32; off > 0; off >>= 1) ss += __shfl_xor(ss, off);
    const float rinv = 1.0f / fmaxf(sqrtf(ss), 1e-12f);
    ushort4 o0, o1;
    o0.x = f2bf(v0.x * rinv); o0.y = f2bf(v0.y * rinv);
    o0.z = f2bf(v0.z * rinv); o0.w = f2bf(v0.w * rinv);
    o1.x = f2bf(v1.x * rinv); o1.y = f2bf(v1.y * rinv);
    o1.z = f2bf(v1.z * rinv); o1.w = f2bf(v1.w * rinv);
    ushort4* op = (ushort4*)(nhat + ((size_t)b * N + n) * DDIM);
    op[lane] = o0;
    op[lane + 64] = o1;
  }
}

// Triangular GEMM lse kernel: 256 threads (4 waves, 2x2), one (pair, batch)
// 128x128 tile per block. A/B staged per-32-K chunk into ring-3 frag-order
// LDS via global_load_lds (wave-uniform dst); counted vmcnt(4) + raw
// s_barrier, prefetch distance 2, never drained mid-loop. 53KB LDS ->
// 3 blocks/CU (12 waves). Only acc in registers.
__global__ __launch_bounds__(256) void lse_kernel(
    const unsigned short* __restrict__ nhat0, const int* __restrict__ labels0,
    const unsigned short* __restrict__ nhat1, const int* __restrict__ labels1,
    float2* __restrict__ sp) {
  __shared__ short8 Abuf[3][512];    // ring-3 x 8 KB, frag-order
  __shared__ short8 Bbuf[3][512];
  __shared__ int labU[128], labV[128];
  __shared__ float2 rowBuf[128][2];  // [row][wc]
  __shared__ float2 colBuf[128][2];  // [col][wr]

  const int tid = threadIdx.x;
  const int p = blockIdx.x >> 6;
  const int b = blockIdx.x & 63;     // batch in low bits: XCD-pinned
  const bool s0 = PAIR_SCALE[p] == 0;
  const int tu = PAIR_TU[p], tv = PAIR_TV[p];
  const bool diag = (tu == tv);
  const int N = s0 ? 640 : 384;
  const unsigned short* nhat = s0 ? nhat0 : nhat1;
  const int* labels = s0 ? labels0 : labels1;
  const int gbase = s0 ? b * 640 : 40960 + b * 384;
  const size_t base = (size_t)b * N * DDIM;

  const int w = tid >> 6, lane = tid & 63;
  const int wr = w >> 1, wc = w & 1;
  const int lrow = lane & 15, lq = lane >> 4;

  if (tid < 128) labU[tid] = labels[tu * 128 + tid];
  else labV[tid - 128] = labels[tv * 128 + (tid - 128)];

  const unsigned short* Asrc = nhat + base + (size_t)tu * 128 * DDIM;
  const unsigned short* Bsrc = nhat + base + (size_t)tv * 128 * DDIM;

  // Stage one 32-K chunk of both panels into ring slot, frag-order.
  // 8 frags/panel/chunk; wave w owns frags f = w*2, w*2+1 (2 A + 2 B loads
  // per wave -> vmcnt granularity 4/chunk/wave). LDS dst is the WAVE-UNIFORM
  // base &buf[f*64]; HW places lane i at +i*16 = element f*64+lane (the MFMA
  // frag layout). Global src per-lane: row = f*16+lrow, k = cc*32 + lq*8.
  #define STAGE(slot, cc)                                                    \
    do {                                                                     \
      _Pragma("unroll")                                                      \
      for (int i = 0; i < 2; ++i) {                                          \
        const int f = w * 2 + i;                                             \
        const size_t so = (size_t)(f * 16 + lrow) * DDIM + (cc) * 32 + lq * 8;\
        async16(Asrc + so, &Abuf[slot][f * 64]);                             \
        async16(Bsrc + so, &Bbuf[slot][f * 64]);                             \
      }                                                                      \
    } while (0)

  f32x4 acc[4][4];
  #pragma unroll
  for (int mi = 0; mi < 4; ++mi)
    #pragma unroll
    for (int ni = 0; ni < 4; ++ni) acc[mi][ni] = (f32x4){0.f, 0.f, 0.f, 0.f};

  STAGE(0, 0);
  STAGE(1, 1);

  #pragma unroll
  for (int c = 0; c < 16; ++c) {
    // Own 4 loads of chunk c done; chunk c+1's 4 stay in flight.
    if (c < 15) asm volatile("s_waitcnt vmcnt(4)" ::: "memory");
    else        asm volatile("s_waitcnt vmcnt(0)" ::: "memory");
    __builtin_amdgcn_s_barrier();   // all waves' chunk-c loads landed;
                                    // all waves done reading chunk c-1
    if (c < 14) STAGE((c + 2) % 3, c + 2);   // refill slot of chunk c-1
    const short8* Ab = &Abuf[c % 3][0];
    const short8* Bb = &Bbuf[c % 3][0];
    short8 am[4], bn[4];
    #pragma unroll
    for (int mi = 0; mi < 4; ++mi) am[mi] = Ab[(wr * 4 + mi) * 64 + lane];
    #pragma unroll
    for (int ni = 0; ni < 4; ++ni) bn[ni] = Bb[(wc * 4 + ni) * 64 + lane];
    #pragma unroll
    for (int mi = 0; mi < 4; ++mi)
      #pragma unroll
      for (int ni = 0; ni < 4; ++ni)
        acc[mi][ni] = __builtin_amdgcn_mfma_f32_16x16x32_bf16(
            am[mi], bn[ni], acc[mi][ni], 0, 0, 0);
  }
  #undef STAGE

  // ---- epilogue: harvest rows (always) and cols (off-diag) ----
  float rSE[4][4], rPOS[4][4];
  float cSE[4] = {0.f, 0.f, 0.f, 0.f};
  float cPOS[4] = {0.f, 0.f, 0.f, 0.f};
  int labn[4][4], labm[4];
  #pragma unroll
  for (int mi = 0; mi < 4; ++mi)
    #pragma unroll
    for (int r = 0; r < 4; ++r) {
      rSE[mi][r] = 0.f; rPOS[mi][r] = 0.f;
      labn[mi][r] = labU[wr * 64 + mi * 16 + lq * 4 + r];
    }
  #pragma unroll
  for (int ni = 0; ni < 4; ++ni) labm[ni] = labV[wc * 64 + ni * 16 + lrow];

  #pragma unroll
  for (int mi = 0; mi < 4; ++mi) {
    const int u_loc = wr * 64 + mi * 16 + lq * 4;
    #pragma unroll
    for (int ni = 0; ni < 4; ++ni) {
      const int v_loc = wc * 64 + ni * 16 + lrow;
      #pragma unroll
      for (int r = 0; r < 4; ++r) {
        const float sim = acc[mi][ni][r] * 10.0f;    // 1/TAU
        const float e = __expf(sim - 10.0f);         // fixed shift (diag max)
        rSE[mi][r] += e;
        const bool match = (labn[mi][r] >= 0) && (labm[ni] == labn[mi][r]);
        const bool self = diag && (u_loc + r == v_loc);
        if (match && !self) rPOS[mi][r] += sim;
        if (!diag) {
          cSE[ni] += e;
          if (match) cPOS[ni] += sim;   // cross-tile: self impossible
        }
      }
    }
  }

  // row reduce across the 16 col-lanes -> lanes lrow==0 hold (mi, lq, r)
  #pragma unroll
  for (int off = 1; off <= 8; off <<= 1)
    #pragma unroll
    for (int mi = 0; mi < 4; ++mi)
      #pragma unroll
      for (int r = 0; r < 4; ++r) {
        rSE[mi][r] += __shfl_xor(rSE[mi][r], off);
        rPOS[mi][r] += __shfl_xor(rPOS[mi][r], off);
      }
  if (lrow == 0) {
    #pragma unroll
    for (int mi = 0; mi < 4; ++mi)
      #pragma unroll
      for (int r = 0; r < 4; ++r) {
        float2 st; st.x = rSE[mi][r]; st.y = rPOS[mi][r];
        rowBuf[wr * 64 + mi * 16 + lq * 4 + r][wc] = st;
      }
  }
  if (!diag) {
    // col reduce across lq groups -> lanes lane<16 hold (ni, lrow)
    #pragma unroll
    for (int off = 16; off <= 32; off <<= 1)
      #pragma unroll
      for (int ni = 0; ni < 4; ++ni) {
        cSE[ni] += __shfl_xor(cSE[ni], off);
        cPOS[ni] += __shfl_xor(cPOS[ni], off);
      }
    if (lane < 16) {
      #pragma unroll
      for (int ni = 0; ni < 4; ++ni) {
        float2 st; st.x = cSE[ni]; st.y = cPOS[ni];
        colBuf[wc * 64 + ni * 16 + lrow][wr] = st;
      }
    }
  }
  __syncthreads();
  if (tid < 128) {
    const float2 ra = rowBuf[tid][0], rb = rowBuf[tid][1];
    float2 st; st.x = ra.x + rb.x; st.y = ra.y + rb.y;
    sp[(size_t)tv * NGID + gbase + tu * 128 + tid] = st;
    if (!diag) {
      const float2 ca = colBuf[tid][0], cb = colBuf[tid][1];
      float2 ct; ct.x = ca.x + cb.x; ct.y = ca.y + cb.y;
      sp[(size_t)tu * NGID + gbase + tv * 128 + tid] = ct;
    }
  }
}

// Per-block label histogram (cnt fused here), then sum per-gid partials over
// slots, apply LSE + pos/cnt, reduce. Last block (ticket) folds final loss.
__global__ __launch_bounds__(256) void loss_reduce(
    const float2* __restrict__ sp, const int* __restrict__ labels0,
    const int* __restrict__ labels1, float* __restrict__ acc,
    int* __restrict__ ticket, float* __restrict__ lossp) {
  __shared__ int lab0[640], lab1[384];
  __shared__ int hist0[128], hist1[64];
  __shared__ int vcS[2];
  __shared__ float r0[4], r1[4];
  const int t = threadIdx.x;
  if (t < 128) hist0[t] = 0;
  else if (t < 192) hist1[t - 128] = 0;
  if (t < 2) vcS[t] = 0;
  for (int i = t; i < 640; i += 256) lab0[i] = labels0[i];
  for (int i = t; i < 384; i += 256) lab1[i] = labels1[i];
  __syncthreads();
  for (int i = t; i < 640; i += 256)
    if (lab0[i] >= 0) atomicAdd(&hist0[lab0[i]], 1);
  for (int i = t; i < 384; i += 256)
    if (lab1[i] >= 0) atomicAdd(&hist1[lab1[i]], 1);
  __syncthreads();
  int lv0 = 0, lv1 = 0;
  for (int i = t; i < 640; i += 256)
    if (lab0[i] >= 0 && hist0[lab0[i]] >= 2) ++lv0;
  for (int i = t; i < 384; i += 256)
    if (lab1[i] >= 0 && hist1[lab1[i]] >= 2) ++lv1;
  if (lv0 > 0) atomicAdd(&vcS[0], lv0);
  if (lv1 > 0) atomicAdd(&vcS[1], lv1);
  __syncthreads();

  float l0 = 0.f, l1 = 0.f;
  for (int g = blockIdx.x * 256 + t; g < NGID; g += 64 * 256) {
    const bool is0 = g < 40960;
    const int n = is0 ? (g % 640) : ((g - 40960) % 384);
    const int nslots = is0 ? 5 : 3;
    float se = 0.f, pos = 0.f;
    for (int s = 0; s < nslots; ++s) {
      const float2 v = sp[(size_t)s * NGID + g];
      se += v.x; pos += v.y;
    }
    const int lb = is0 ? lab0[n] : lab1[n];
    const int c = (lb >= 0) ? ((is0 ? hist0[lb] : hist1[lb]) - 1) : 0;
    if (c > 0) {
      const float v = (10.0f + logf(se)) - pos / (float)c;
      if (is0) l0 += v; else l1 += v;
    }
  }
  #pragma unroll
  for (int off = 32; off > 0; off >>= 1) {
    l0 += __shfl_xor(l0, off);
    l1 += __shfl_xor(l1, off);
  }
  if ((t & 63) == 0) { r0[t >> 6] = l0; r1[t >> 6] = l1; }
  __syncthreads();
  if (t == 0) {
    atomicAdd(&acc[0], r0[0] + r0[1] + r0[2] + r0[3]);
    atomicAdd(&acc[1], r1[0] + r1[1] + r1[2] + r1[3]);
    __threadfence();
    const int done = atomicAdd(ticket, 1);
    if (done == 63) {   // last block: fold final loss (atomic reads only)
      const float a0v = atomicAdd(&acc[0], 0.0f);
      const float a1v = atomicAdd(&acc[1], 0.0f);
      float l = 0.f;
      if (vcS[0] > 0) l += a0v / (float)(BATCH * vcS[0]);
      if (vcS[1] > 0) l += a1v / (float)(BATCH * vcS[1]);
      lossp[0] = l;
    }
  }
}

extern "C" void kernel_launch(void* const* d_in, const int* in_sizes, int n_in,
                              void* d_out, int out_size, void* d_ws,
                              size_t ws_size, hipStream_t stream) {
  const float* x0 = (const float*)d_in[0];
  const float* x1 = (const float*)d_in[1];
  const float* w0 = (const float*)d_in[2];
  const float* w1 = (const float*)d_in[3];
  const float* ehy0 = (const float*)d_in[4];
  const float* ehy1 = (const float*)d_in[5];
  const float* enod0 = (const float*)d_in[6];
  const float* enod1 = (const float*)d_in[7];

  float* out = (float*)d_out;
  float* adj0 = out;                       // 640*128
  float* adj1 = out + 640 * 128;           // 384*64
  float* lossp = out + 640 * 128 + 384 * 64;

  unsigned short* nhat0 = (unsigned short*)d_ws;
  unsigned short* nhat1 = nhat0 + (size_t)BATCH * 640 * DDIM;
  int* ip = (int*)(nhat1 + (size_t)BATCH * 384 * DDIM);
  int* labels0 = ip;
  int* labels1 = labels0 + 640;
  int* ticket = labels1 + 384;
  float* acc = (float*)(ticket + 1);
  float2* sp = (float2*)((((size_t)(acc + 2)) + 255) & ~(size_t)255);
  // sp: 5 slots x 65536 gids x 8 B = 2.6 MB (ws total ~58 MB)

  prep_kernel<<<1024 + 16384, 256, 0, stream>>>(
      enod0, ehy0, enod1, ehy1, adj0, adj1, labels0, labels1,
      x0, w0, x1, w1, nhat0, nhat1, acc, ticket);
  lse_kernel<<<1344, 256, 0, stream>>>(nhat0, labels0, nhat1, labels1, sp);
  loss_reduce<<<64, 256, 0, stream>>>(sp, labels0, labels1, acc, ticket,
                                      lossp);
}

// Round 9
// 234.539 us; speedup vs baseline: 1.0136x; 1.0136x over previous
//
#include <hip/hip_runtime.h>

// incidence_matrix_learn on MI355X — round 17.
// Round-16 post-mortem: (a) lse 3rd block never fit — 54272B x 3 needs all
// but 1KB of LDS; occupancy stayed 18% while barrier count doubled -> 73us.
// (b) total - lse ~= 164us EVERY round while prep never cracks top-5
// (<73us each) and prep's pipe work is only ~35us: prep's 17408 tiny
// workgroups are dispatch-bound (Guideline 11: cap ~2048 blocks and
// grid-stride). Fixes: (1) prep = 2048 blocks, normalize waves grid-stride
// 16 rows each (literal-divisor 640/384 split); (2) lse LDS 54272->49152
// (labels preloaded to regs + explicit vmcnt(0) drain to keep counted waits
// exact; rowBuf/colBuf aliased into staging, barrier-after-K-loop) -> true
// 3 blocks/CU with ring-3 counted-vmcnt pipeline kept; (3) loss_reduce
// unchanged. Accumulation order unchanged -> bitwise-identical output.
// Validated algebra (rounds 1-16, absmax 0.0): top-k no-op; P via labels;
// fixed-shift-10 LSE (denom includes self; pos excludes); bf16 nhat;
// cnt = label-histogram - 1; disjoint sp slots; frag-order LDS staging;
// wave-uniform global_load_lds dst; counted vmcnt(4) ring-3 discipline.

#define DDIM 512
#define BATCH 64
#define NGID 65536   // 64*640 + 64*384 node-row slots across both scales

typedef __attribute__((ext_vector_type(8))) short short8;
typedef __attribute__((ext_vector_type(4))) float f32x4;

// Triangular tile-pair list (128-granularity): 15 scale0 + 6 scale1.
__constant__ int PAIR_SCALE[21] = {0,0,0,0,0,0,0,0,0,0,0,0,0,0,0, 1,1,1,1,1,1};
__constant__ int PAIR_TU[21]    = {0,0,0,0,0,1,1,1,1,2,2,2,3,3,4, 0,0,0,1,1,2};
__constant__ int PAIR_TV[21]    = {0,1,2,3,4,1,2,3,4,2,3,4,3,4,4, 0,1,2,1,2,2};

__device__ __forceinline__ unsigned short f2bf(float f) {
  unsigned int u = __float_as_uint(f);
  u += 0x7fffu + ((u >> 16) & 1u);   // RNE
  return (unsigned short)(u >> 16);
}

__device__ __forceinline__ void async16(const void* g, void* l) {
  __builtin_amdgcn_global_load_lds(
      (const __attribute__((address_space(1))) unsigned int*)g,
      (__attribute__((address_space(3))) unsigned int*)l, 16, 0, 0);
}

// Fused prep kernel, 2048 blocks x 256 threads. Blocks [0,1024): adj (both
// scales) + acc/ticket init. Blocks [1024,2048): normalize, one WAVE per
// node row, grid-strided 16 rows per wave (dispatch-overhead fix).
__global__ __launch_bounds__(256) void prep_kernel(
    const float* __restrict__ enod0, const float* __restrict__ ehy0,
    const float* __restrict__ enod1, const float* __restrict__ ehy1,
    float* __restrict__ adj0, float* __restrict__ adj1,
    int* __restrict__ labels0, int* __restrict__ labels1,
    const float* __restrict__ x0, const float* __restrict__ w0,
    const float* __restrict__ x1, const float* __restrict__ w1,
    unsigned short* __restrict__ nhat0, unsigned short* __restrict__ nhat1,
    float* __restrict__ acc, int* __restrict__ ticket) {
  const int t = threadIdx.x;
  if (blockIdx.x < 1024) {
    // ---- adj path ----
    if (blockIdx.x == 0 && t == 0) { acc[0] = 0.f; acc[1] = 0.f; ticket[0] = 0; }
    const bool s0 = blockIdx.x < 640;
    const int n = s0 ? blockIdx.x : blockIdx.x - 640;
    const int H = s0 ? 128 : 64;
    const float* enod = s0 ? enod0 : enod1;
    const float* ehy = s0 ? ehy0 : ehy1;
    float* out_adj = s0 ? adj0 : adj1;
    int* labels = s0 ? labels0 : labels1;
    __shared__ float erow[DDIM];
    __shared__ float red[128];
    __shared__ int lab;
    if (t < 128) ((float4*)erow)[t] = ((const float4*)(enod + (size_t)n * DDIM))[t];
    if (t == 0) lab = -1;
    __syncthreads();
    float v = 0.f;
    if (t < H) {
      const float4* hr = (const float4*)(ehy + (size_t)t * DDIM);
      float a = 0.f;
      #pragma unroll 8
      for (int d = 0; d < DDIM / 4; ++d) {
        float4 h = hr[d];
        float4 e = ((const float4*)erow)[d];
        a = fmaf(h.x, e.x, a); a = fmaf(h.y, e.y, a);
        a = fmaf(h.z, e.z, a); a = fmaf(h.w, e.w, a);
      }
      v = fmaxf(0.f, 3.0f * a);
    }
    if (t < 128) red[t] = v;
    __syncthreads();
    for (int s = 64; s > 0; s >>= 1) {
      if (t < s) red[t] = fmaxf(red[t], red[t + s]);
      __syncthreads();
    }
    const float mx = red[0];
    __syncthreads();
    const float e = (t < H) ? __expf(v - mx) : 0.f;
    if (t < 128) red[t] = e;
    __syncthreads();
    for (int s = 64; s > 0; s >>= 1) {
      if (t < s) red[t] += red[t + s];
      __syncthreads();
    }
    const float sum = red[0];
    if (t < H) {
      const float adj = e / sum;
      const float bin = (adj > 0.5f) ? 1.0f : 0.0f;
      out_adj[(size_t)n * H + t] = bin;
      if (bin > 0.f) lab = t;
    }
    __syncthreads();
    if (t == 0) labels[n] = lab;
  } else {
    // ---- normalize path: wave per row, 16 rows per wave ----
    const int wave = t >> 6;
    const int lane = t & 63;
    const int wid = (blockIdx.x - 1024) * 4 + wave;   // 0..4095
    for (int it = 0; it < 16; ++it) {
      const int g = wid + it * 4096;   // < 65536
      const float* src;
      unsigned short* dst;
      if (g < BATCH * 640) {
        const int b = g / 640;          // literal divisor -> magic-mul
        const int n = g - b * 640;
        src = (n < 512) ? (x0 + ((size_t)b * 512 + n) * DDIM)
                        : (w0 + (size_t)(n - 512) * DDIM);
        dst = nhat0 + ((size_t)b * 640 + n) * DDIM;
      } else {
        const int gg = g - BATCH * 640;
        const int b = gg / 384;         // literal divisor -> magic-mul
        const int n = gg - b * 384;
        src = (n < 256) ? (x1 + ((size_t)b * 256 + n) * DDIM)
                        : (w1 + (size_t)(n - 256) * DDIM);
        dst = nhat1 + ((size_t)b * 384 + n) * DDIM;
      }
      const float4* rowp = (const float4*)src;
      const float4 v0 = rowp[lane];
      const float4 v1 = rowp[lane + 64];
      float ss = v0.x * v0.x + v0.y * v0.y + v0.z * v0.z + v0.w * v0.w +
                 v1.x * v1.x + v1.y * v1.y + v1.z * v1.z + v1.w * v1.w;
      #pragma unroll
      for (int off = 32; off > 0; off >>= 1) ss += __shfl_xor(ss, off);
      const float rinv = 1.0f / fmaxf(sqrtf(ss), 1e-12f);
      ushort4 o0, o1;
      o0.x = f2bf(v0.x * rinv); o0.y = f2bf(v0.y * rinv);
      o0.z = f2bf(v0.z * rinv); o0.w = f2bf(v0.w * rinv);
      o1.x = f2bf(v1.x * rinv); o1.y = f2bf(v1.y * rinv);
      o1.z = f2bf(v1.z * rinv); o1.w = f2bf(v1.w * rinv);
      ushort4* op = (ushort4*)dst;
      op[lane] = o0;
      op[lane + 64] = o1;
    }
  }
}

// Triangular GEMM lse kernel: 256 threads (4 waves, 2x2), one (pair, batch)
// 128x128 tile per block. A/B staged per-32-K chunk into ring-3 frag-order
// LDS via global_load_lds (wave-uniform dst); counted vmcnt(4) + raw
// s_barrier, prefetch distance 2, never drained mid-loop. LDS = 48KB flat
// (staging; epilogue row/col buffers aliased in after the K-loop) -> 3
// blocks/CU (12 waves). Labels preloaded to registers (explicit vmcnt(0)
// drain keeps the counted waits exact). Only acc in registers.
__global__ __launch_bounds__(256) void lse_kernel(
    const unsigned short* __restrict__ nhat0, const int* __restrict__ labels0,
    const unsigned short* __restrict__ nhat1, const int* __restrict__ labels1,
    float2* __restrict__ sp) {
  __shared__ char smem[49152];   // 3 slots x (A 8KB + B 8KB), frag-order

  const int tid = threadIdx.x;
  const int p = blockIdx.x >> 6;
  const int b = blockIdx.x & 63;     // batch in low bits: XCD-pinned
  const bool s0 = PAIR_SCALE[p] == 0;
  const int tu = PAIR_TU[p], tv = PAIR_TV[p];
  const bool diag = (tu == tv);
  const int N = s0 ? 640 : 384;
  const unsigned short* nhat = s0 ? nhat0 : nhat1;
  const int* labels = s0 ? labels0 : labels1;
  const int gbase = s0 ? b * 640 : 40960 + b * 384;
  const size_t base = (size_t)b * N * DDIM;

  const int w = tid >> 6, lane = tid & 63;
  const int wr = w >> 1, wc = w & 1;
  const int lrow = lane & 15, lq = lane >> 4;

  // Preload labels into registers (before any staging).
  int labn[4][4], labm[4];
  #pragma unroll
  for (int mi = 0; mi < 4; ++mi)
    #pragma unroll
    for (int r = 0; r < 4; ++r)
      labn[mi][r] = labels[tu * 128 + wr * 64 + mi * 16 + lq * 4 + r];
  #pragma unroll
  for (int ni = 0; ni < 4; ++ni)
    labm[ni] = labels[tv * 128 + wc * 64 + ni * 16 + lrow];
  // Drain label loads so the counted vmcnt discipline below is exact.
  asm volatile("s_waitcnt vmcnt(0)" ::: "memory");

  const unsigned short* Asrc = nhat + base + (size_t)tu * 128 * DDIM;
  const unsigned short* Bsrc = nhat + base + (size_t)tv * 128 * DDIM;

  // Stage one 32-K chunk of both panels into ring slot, frag-order.
  // 8 frags/panel/chunk; wave w owns frags f = w*2, w*2+1 (2 A + 2 B loads
  // per wave -> vmcnt granularity 4/chunk/wave). LDS dst is the WAVE-UNIFORM
  // base; HW places lane i at +i*16 = element f*64+lane (MFMA frag layout).
  // Global src per-lane: row = f*16+lrow, k = cc*32 + lq*8.
  #define SLOTA(s) ((short8*)(smem + (s) * 16384))
  #define SLOTB(s) ((short8*)(smem + (s) * 16384 + 8192))
  #define STAGE(slot, cc)                                                    \
    do {                                                                     \
      _Pragma("unroll")                                                      \
      for (int i = 0; i < 2; ++i) {                                          \
        const int f = w * 2 + i;                                             \
        const size_t so = (size_t)(f * 16 + lrow) * DDIM + (cc) * 32 + lq * 8;\
        async16(Asrc + so, SLOTA(slot) + f * 64);                            \
        async16(Bsrc + so, SLOTB(slot) + f * 64);                            \
      }                                                                      \
    } while (0)

  f32x4 acc[4][4];
  #pragma unroll
  for (int mi = 0; mi < 4; ++mi)
    #pragma unroll
    for (int ni = 0; ni < 4; ++ni) acc[mi][ni] = (f32x4){0.f, 0.f, 0.f, 0.f};

  STAGE(0, 0);
  STAGE(1, 1);

  #pragma unroll
  for (int c = 0; c < 16; ++c) {
    // Own 4 loads of chunk c done; chunk c+1's 4 stay in flight.
    if (c < 15) asm volatile("s_waitcnt vmcnt(4)" ::: "memory");
    else        asm volatile("s_waitcnt vmcnt(0)" ::: "memory");
    __builtin_amdgcn_s_barrier();   // all waves' chunk-c loads landed;
                                    // all waves done reading chunk c-1
    if (c < 14) STAGE((c + 2) % 3, c + 2);   // refill slot of chunk c-1
    const short8* Ab = SLOTA(c % 3);
    const short8* Bb = SLOTB(c % 3);
    short8 am[4], bn[4];
    #pragma unroll
    for (int mi = 0; mi < 4; ++mi) am[mi] = Ab[(wr * 4 + mi) * 64 + lane];
    #pragma unroll
    for (int ni = 0; ni < 4; ++ni) bn[ni] = Bb[(wc * 4 + ni) * 64 + lane];
    #pragma unroll
    for (int mi = 0; mi < 4; ++mi)
      #pragma unroll
      for (int ni = 0; ni < 4; ++ni)
        acc[mi][ni] = __builtin_amdgcn_mfma_f32_16x16x32_bf16(
            am[mi], bn[ni], acc[mi][ni], 0, 0, 0);
  }
  #undef STAGE

  __syncthreads();   // all LDS reads done -> safe to alias epilogue buffers
  float2 (*rowBuf)[2] = (float2(*)[2])smem;            // 2 KB
  float2 (*colBuf)[2] = (float2(*)[2])(smem + 2048);   // 2 KB

  // ---- epilogue: harvest rows (always) and cols (off-diag) ----
  float rSE[4][4], rPOS[4][4];
  float cSE[4] = {0.f, 0.f, 0.f, 0.f};
  float cPOS[4] = {0.f, 0.f, 0.f, 0.f};
  #pragma unroll
  for (int mi = 0; mi < 4; ++mi)
    #pragma unroll
    for (int r = 0; r < 4; ++r) { rSE[mi][r] = 0.f; rPOS[mi][r] = 0.f; }

  #pragma unroll
  for (int mi = 0; mi < 4; ++mi) {
    const int u_loc = wr * 64 + mi * 16 + lq * 4;
    #pragma unroll
    for (int ni = 0; ni < 4; ++ni) {
      const int v_loc = wc * 64 + ni * 16 + lrow;
      #pragma unroll
      for (int r = 0; r < 4; ++r) {
        const float sim = acc[mi][ni][r] * 10.0f;    // 1/TAU
        const float e = __expf(sim - 10.0f);         // fixed shift (diag max)
        rSE[mi][r] += e;
        const bool match = (labn[mi][r] >= 0) && (labm[ni] == labn[mi][r]);
        const bool self = diag && (u_loc + r == v_loc);
        if (match && !self) rPOS[mi][r] += sim;
        if (!diag) {
          cSE[ni] += e;
          if (match) cPOS[ni] += sim;   // cross-tile: self impossible
        }
      }
    }
  }

  // row reduce across the 16 col-lanes -> lanes lrow==0 hold (mi, lq, r)
  #pragma unroll
  for (int off = 1; off <= 8; off <<= 1)
    #pragma unroll
    for (int mi = 0; mi < 4; ++mi)
      #pragma unroll
      for (int r = 0; r < 4; ++r) {
        rSE[mi][r] += __shfl_xor(rSE[mi][r], off);
        rPOS[mi][r] += __shfl_xor(rPOS[mi][r], off);
      }
  if (lrow == 0) {
    #pragma unroll
    for (int mi = 0; mi < 4; ++mi)
      #pragma unroll
      for (int r = 0; r < 4; ++r) {
        float2 st; st.x = rSE[mi][r]; st.y = rPOS[mi][r];
        rowBuf[wr * 64 + mi * 16 + lq * 4 + r][wc] = st;
      }
  }
  if (!diag) {
    // col reduce across lq groups -> lanes lane<16 hold (ni, lrow)
    #pragma unroll
    for (int off = 16; off <= 32; off <<= 1)
      #pragma unroll
      for (int ni = 0; ni < 4; ++ni) {
        cSE[ni] += __shfl_xor(cSE[ni], off);
        cPOS[ni] += __shfl_xor(cPOS[ni], off);
      }
    if (lane < 16) {
      #pragma unroll
      for (int ni = 0; ni < 4; ++ni) {
        float2 st; st.x = cSE[ni]; st.y = cPOS[ni];
        colBuf[wc * 64 + ni * 16 + lrow][wr] = st;
      }
    }
  }
  __syncthreads();
  if (tid < 128) {
    const float2 ra = rowBuf[tid][0], rb = rowBuf[tid][1];
    float2 st; st.x = ra.x + rb.x; st.y = ra.y + rb.y;
    sp[(size_t)tv * NGID + gbase + tu * 128 + tid] = st;
    if (!diag) {
      const float2 ca = colBuf[tid][0], cb = colBuf[tid][1];
      float2 ct; ct.x = ca.x + cb.x; ct.y = ca.y + cb.y;
      sp[(size_t)tu * NGID + gbase + tv * 128 + tid] = ct;
    }
  }
}

// Per-block label histogram (cnt fused here), then sum per-gid partials over
// slots, apply LSE + pos/cnt, reduce. Last block (ticket) folds final loss.
__global__ __launch_bounds__(256) void loss_reduce(
    const float2* __restrict__ sp, const int* __restrict__ labels0,
    const int* __restrict__ labels1, float* __restrict__ acc,
    int* __restrict__ ticket, float* __restrict__ lossp) {
  __shared__ int lab0[640], lab1[384];
  __shared__ int hist0[128], hist1[64];
  __shared__ int vcS[2];
  __shared__ float r0[4], r1[4];
  const int t = threadIdx.x;
  if (t < 128) hist0[t] = 0;
  else if (t < 192) hist1[t - 128] = 0;
  if (t < 2) vcS[t] = 0;
  for (int i = t; i < 640; i += 256) lab0[i] = labels0[i];
  for (int i = t; i < 384; i += 256) lab1[i] = labels1[i];
  __syncthreads();
  for (int i = t; i < 640; i += 256)
    if (lab0[i] >= 0) atomicAdd(&hist0[lab0[i]], 1);
  for (int i = t; i < 384; i += 256)
    if (lab1[i] >= 0) atomicAdd(&hist1[lab1[i]], 1);
  __syncthreads();
  int lv0 = 0, lv1 = 0;
  for (int i = t; i < 640; i += 256)
    if (lab0[i] >= 0 && hist0[lab0[i]] >= 2) ++lv0;
  for (int i = t; i < 384; i += 256)
    if (lab1[i] >= 0 && hist1[lab1[i]] >= 2) ++lv1;
  if (lv0 > 0) atomicAdd(&vcS[0], lv0);
  if (lv1 > 0) atomicAdd(&vcS[1], lv1);
  __syncthreads();

  float l0 = 0.f, l1 = 0.f;
  for (int g = blockIdx.x * 256 + t; g < NGID; g += 64 * 256) {
    const bool is0 = g < 40960;
    const int n = is0 ? (g % 640) : ((g - 40960) % 384);
    const int nslots = is0 ? 5 : 3;
    float se = 0.f, pos = 0.f;
    for (int s = 0; s < nslots; ++s) {
      const float2 v = sp[(size_t)s * NGID + g];
      se += v.x; pos += v.y;
    }
    const int lb = is0 ? lab0[n] : lab1[n];
    const int c = (lb >= 0) ? ((is0 ? hist0[lb] : hist1[lb]) - 1) : 0;
    if (c > 0) {
      const float v = (10.0f + logf(se)) - pos / (float)c;
      if (is0) l0 += v; else l1 += v;
    }
  }
  #pragma unroll
  for (int off = 32; off > 0; off >>= 1) {
    l0 += __shfl_xor(l0, off);
    l1 += __shfl_xor(l1, off);
  }
  if ((t & 63) == 0) { r0[t >> 6] = l0; r1[t >> 6] = l1; }
  __syncthreads();
  if (t == 0) {
    atomicAdd(&acc[0], r0[0] + r0[1] + r0[2] + r0[3]);
    atomicAdd(&acc[1], r1[0] + r1[1] + r1[2] + r1[3]);
    __threadfence();
    const int done = atomicAdd(ticket, 1);
    if (done == 63) {   // last block: fold final loss (atomic reads only)
      const float a0v = atomicAdd(&acc[0], 0.0f);
      const float a1v = atomicAdd(&acc[1], 0.0f);
      float l = 0.f;
      if (vcS[0] > 0) l += a0v / (float)(BATCH * vcS[0]);
      if (vcS[1] > 0) l += a1v / (float)(BATCH * vcS[1]);
      lossp[0] = l;
    }
  }
}

extern "C" void kernel_launch(void* const* d_in, const int* in_sizes, int n_in,
                              void* d_out, int out_size, void* d_ws,
                              size_t ws_size, hipStream_t stream) {
  const float* x0 = (const float*)d_in[0];
  const float* x1 = (const float*)d_in[1];
  const float* w0 = (const float*)d_in[2];
  const float* w1 = (const float*)d_in[3];
  const float* ehy0 = (const float*)d_in[4];
  const float* ehy1 = (const float*)d_in[5];
  const float* enod0 = (const float*)d_in[6];
  const float* enod1 = (const float*)d_in[7];

  float* out = (float*)d_out;
  float* adj0 = out;                       // 640*128
  float* adj1 = out + 640 * 128;           // 384*64
  float* lossp = out + 640 * 128 + 384 * 64;

  unsigned short* nhat0 = (unsigned short*)d_ws;
  unsigned short* nhat1 = nhat0 + (size_t)BATCH * 640 * DDIM;
  int* ip = (int*)(nhat1 + (size_t)BATCH * 384 * DDIM);
  int* labels0 = ip;
  int* labels1 = labels0 + 640;
  int* ticket = labels1 + 384;
  float* acc = (float*)(ticket + 1);
  float2* sp = (float2*)((((size_t)(acc + 2)) + 255) & ~(size_t)255);
  // sp: 5 slots x 65536 gids x 8 B = 2.6 MB (ws total ~58 MB)

  prep_kernel<<<2048, 256, 0, stream>>>(
      enod0, ehy0, enod1, ehy1, adj0, adj1, labels0, labels1,
      x0, w0, x1, w1, nhat0, nhat1, acc, ticket);
  lse_kernel<<<1344, 256, 0, stream>>>(nhat0, labels0, nhat1, labels1, sp);
  loss_reduce<<<64, 256, 0, stream>>>(sp, labels0, labels1, acc, ticket,
                                      lossp);
}